// Round 4
// baseline (477.797 us; speedup 1.0000x reference)
//
#include <hip/hip_runtime.h>
#include <cstdint>
#include <cstddef>

// Problem: L=4, B=8, S=1024, D=256, H=8, DH=32, I=1024, M=4. bf16 MFMA compute.
#define SS 1024
#define DD 256

typedef unsigned short u16;
typedef __bf16 bf16x8 __attribute__((ext_vector_type(8)));
typedef float f32x4 __attribute__((ext_vector_type(4)));
typedef unsigned short us4 __attribute__((ext_vector_type(4)));

typedef __attribute__((address_space(3))) void lds_void_t;
typedef __attribute__((address_space(1))) const void gvoid_t;

__device__ __forceinline__ u16 f2bf(float f) {
  unsigned u = __builtin_bit_cast(unsigned, f);
  u += 0x7fffu + ((u >> 16) & 1u);     // RNE
  return (u16)(u >> 16);
}
__device__ __forceinline__ u16 f2bf_fast(float f) {  // round-half-away, 2 ops
  unsigned u = __builtin_bit_cast(unsigned, f) + 0x8000u;
  return (u16)(u >> 16);
}
__device__ __forceinline__ float bf2f(u16 h) {
  return __builtin_bit_cast(float, ((unsigned)h) << 16);
}
__device__ __forceinline__ void gld_lds16(const void* g, void* l) {
  __builtin_amdgcn_global_load_lds((gvoid_t*)g, (lds_void_t*)l, 16, 0, 0);
}
// DPP cross-lane within 16-lane rows (VALU-pipe)
template <int CTRL>
__device__ __forceinline__ float dppf(float x) {
  int i = __builtin_bit_cast(int, x);
  int r = __builtin_amdgcn_update_dpp(i, i, CTRL, 0xf, 0xf, false);
  return __builtin_bit_cast(float, r);
}
__device__ __forceinline__ float row_sum16(float v) {
  v += dppf<0x121>(v);
  v += dppf<0x122>(v);
  v += dppf<0x124>(v);
  v += dppf<0x128>(v);
  return v;
}
// tanh-form GELU: max abs err ~3e-4 vs exact erf form (way under threshold)
__device__ __forceinline__ float gelu_f(float x) {
  float x2 = x * x;
  float y = x * (0.7978845608028654f + 0.0356774081363f * x2);
  float e = exp2f(fminf(-2.8853900817779268f * y, 88.f));  // exp(-2y) in exp2 dom
  float th = (1.f - e) * __builtin_amdgcn_rcpf(1.f + e);
  return 0.5f * x * (1.f + th);
}

// ---------------- weight/bias conversion (fp32 -> bf16, or fp32 copy) -------
// dst index remap: off = (i >> sh) * ls + (i & ((1<<sh)-1))   (units: 4-elem)
struct CvtArgs {
  const float* src[9];
  void* dst[9];
  int n4[9];   // number of float4 elements (multiple of 256)
  int bf[9];   // 1 = convert to bf16, 0 = fp32 copy
  int sh[9];   // log2 of per-layer chunk (in 4-elem units)
  int ls[9];   // dst layer stride (in 4-elem units)
};

__global__ __launch_bounds__(256) void cvt_kernel(CvtArgs a) {
  int g = blockIdx.y;
  int i = blockIdx.x * 256 + threadIdx.x;
  if (i >= a.n4[g]) return;                 // block-uniform (n4 % 256 == 0)
  int off = (i >> a.sh[g]) * a.ls[g] + (i & ((1 << a.sh[g]) - 1));
  float4 v = ((const float4*)a.src[g])[i];
  if (a.bf[g]) {
    us4 o; o.x = f2bf(v.x); o.y = f2bf(v.y); o.z = f2bf(v.z); o.w = f2bf(v.w);
    ((us4*)a.dst[g])[off] = o;
  } else {
    ((float4*)a.dst[g])[off] = v;
  }
}

// ---------------- embedding: h = emb_w[x] + pe  (bf16 out) ------------------
__global__ __launch_bounds__(256)
void embed_kernel(const int* __restrict__ x, const float* __restrict__ emb,
                  const float* __restrict__ pe, u16* __restrict__ h) {
  int wave = threadIdx.x >> 6, lane = threadIdx.x & 63;
  int row = blockIdx.x * 4 + wave;          // 0..8191
  int s = row & (SS - 1);
  int tok = x[row];
  float4 e = *(const float4*)(emb + (size_t)tok * DD + lane * 4);
  float4 p = *(const float4*)(pe + (size_t)s * DD + lane * 4);
  us4 o; o.x = f2bf(e.x + p.x); o.y = f2bf(e.y + p.y);
  o.z = f2bf(e.z + p.z); o.w = f2bf(e.w + p.w);
  *(us4*)(h + (size_t)row * DD + lane * 4) = o;
}

#define Q_SCALE (0.17677669529663689f * 1.4426950408889634f)  // rsqrt(DH)*log2e

// ---------------- fused QKV: 32 token-rows per block, B direct from global --
// A (h rows) held in registers for all of K; W[768,256] streamed L2->regs.
// Epilogues: z=0 Q scaled, z=1 K, z=2 V written transposed Vt[b,h,d,s].
__global__ __launch_bounds__(256, 1)
void qkv_kernel(const u16* __restrict__ hb, const u16* __restrict__ w,
                const float* __restrict__ bias, u16* __restrict__ q,
                u16* __restrict__ kout, u16* __restrict__ vt) {
  const int m0 = blockIdx.x * 32;
  const int tid = threadIdx.x;
  const int l15 = tid & 15, quad = (tid & 63) >> 4, wave = tid >> 6;

  bf16x8 a1[2][8];
#pragma unroll
  for (int i = 0; i < 2; ++i)
#pragma unroll
    for (int k = 0; k < 8; ++k)
      a1[i][k] = *(const bf16x8*)(hb + (size_t)(m0 + i * 16 + l15) * DD + k * 32 + quad * 8);

  const f32x4 fzero = {0.f, 0.f, 0.f, 0.f};
#pragma unroll
  for (int g = 0; g < 3; ++g) {
    f32x4 acc[2][4];
#pragma unroll
    for (int i = 0; i < 2; ++i)
#pragma unroll
      for (int j = 0; j < 4; ++j) acc[i][j] = fzero;
#pragma unroll
    for (int k = 0; k < 8; ++k) {
#pragma unroll
      for (int j = 0; j < 4; ++j) {
        int n = wave * 192 + g * 64 + j * 16 + l15;
        bf16x8 b = *(const bf16x8*)(w + (size_t)n * 256 + k * 32 + quad * 8);
        acc[0][j] = __builtin_amdgcn_mfma_f32_16x16x32_bf16(a1[0][k], b, acc[0][j], 0, 0, 0);
        acc[1][j] = __builtin_amdgcn_mfma_f32_16x16x32_bf16(a1[1][k], b, acc[1][j], 0, 0, 0);
      }
    }
#pragma unroll
    for (int j = 0; j < 4; ++j) {
      int nb = wave * 192 + g * 64 + j * 16;   // wave-uniform; z uniform per (g,j)
      int z = nb >> 8;
      float bj = bias[nb + l15];
      if (z == 0) {
        int n = (nb & 255) + l15;
#pragma unroll
        for (int i = 0; i < 2; ++i)
#pragma unroll
          for (int r = 0; r < 4; ++r) {
            int tok = m0 + i * 16 + quad * 4 + r;
            q[(size_t)tok * 256 + n] = f2bf((acc[i][j][r] + bj) * Q_SCALE);
          }
      } else if (z == 1) {
        int n = (nb & 255) + l15;
#pragma unroll
        for (int i = 0; i < 2; ++i)
#pragma unroll
          for (int r = 0; r < 4; ++r) {
            int tok = m0 + i * 16 + quad * 4 + r;
            kout[(size_t)tok * 256 + n] = f2bf(acc[i][j][r] + bj);
          }
      } else {
        int dcol = (nb & 255) + l15;     // 0..255 -> h = dcol>>5, d = dcol&31
#pragma unroll
        for (int i = 0; i < 2; ++i) {
          int tok0 = m0 + i * 16 + quad * 4;
          int bb = tok0 >> 10, s0 = tok0 & 1023;
          us4 o;
          o.x = f2bf(acc[i][j][0] + bj);
          o.y = f2bf(acc[i][j][1] + bj);
          o.z = f2bf(acc[i][j][2] + bj);
          o.w = f2bf(acc[i][j][3] + bj);
          *(us4*)(vt + ((size_t)(bb * 8 + (dcol >> 5)) * 32 + (dcol & 31)) * SS + s0) = o;
        }
      }
    }
  }
}

// ---------------- flash-style causal attention (max-free softmax) -----------
__global__ __launch_bounds__(256)
void attn_kernel(const u16* __restrict__ Q, const u16* __restrict__ Km,
                 const u16* __restrict__ Vt, u16* __restrict__ ctx) {
  const int tid = threadIdx.x;
  const int l15 = tid & 15;
  const int quad = (tid & 63) >> 4;
  const int wave = tid >> 6;
  const int y = blockIdx.y;
  const int qt = 15 - (((int)blockIdx.x + ((y >> 4) << 2)) & 15);  // long-first, CU-balanced
  const int q0 = qt * 64;
  const int b = y >> 3, h = y & 7;
  const int q0w = q0 + wave * 16;

  __shared__ __align__(16) u16 sK[2][64 * 40];   // [key][d] stride 40 u16
  __shared__ __align__(16) u16 sV[2][32 * 72];   // [d][key] stride 72 u16
  __shared__ __align__(16) u16 sP[4][16 * 72];   // per-wave [q][key]
  u16* sPw = sP[wave];

  bf16x8 qf = *(const bf16x8*)(Q + ((size_t)(b * SS + q0w + l15)) * DD + h * 32 + quad * 8);

  const int krow = tid >> 2, kch = tid & 3;   // K staging: 64 rows x 4 x 16B
  const int vd = tid >> 3, vch = tid & 7;     // V staging: 32 d x 8 x 16B
  const u16* Kbase = Km + (size_t)(b * SS) * DD + h * 32;
  const u16* Vbase = Vt + ((size_t)y * 32 + vd) * SS;

  uint4 kreg = *(const uint4*)(Kbase + (size_t)krow * DD + kch * 8);
  uint4 vreg = *(const uint4*)(Vbase + vch * 8);

  f32x4 o0 = {0.f, 0.f, 0.f, 0.f}, o1 = {0.f, 0.f, 0.f, 0.f};
  const f32x4 fzero = {0.f, 0.f, 0.f, 0.f};
  float rs[4] = {0.f, 0.f, 0.f, 0.f};

  const int nt = q0 >> 6;
  for (int it = 0; it <= nt; ++it) {
    const int bsel = it & 1;
    *(uint4*)((char*)sK[bsel] + krow * 80 + kch * 16) = kreg;
    *(uint4*)((char*)sV[bsel] + vd * 144 + vch * 16) = vreg;
    if (it < nt) {
      int kb = (it + 1) * 64;
      kreg = *(const uint4*)(Kbase + (size_t)(kb + krow) * DD + kch * 8);
      vreg = *(const uint4*)(Vbase + kb + vch * 8);
    }
    __syncthreads();

    f32x4 s4[4];
#pragma unroll
    for (int t = 0; t < 4; ++t) {
      bf16x8 kf = *(const bf16x8*)((const char*)sK[bsel] + (t * 16 + l15) * 80 + quad * 16);
      s4[t] = __builtin_amdgcn_mfma_f32_16x16x32_bf16(qf, kf, fzero, 0, 0, 0);
    }
    if (it == nt) {
#pragma unroll
      for (int t = 0; t < 4; ++t) {
        int key = it * 64 + t * 16 + l15;
#pragma unroll
        for (int r = 0; r < 4; ++r) {
          int qr = q0w + quad * 4 + r;
          float p = exp2f(s4[t][r]);
          p = (key > qr) ? 0.f : p;
          s4[t][r] = p;
          rs[r] += p;
        }
      }
    } else {
#pragma unroll
      for (int t = 0; t < 4; ++t)
#pragma unroll
        for (int r = 0; r < 4; ++r) {
          float p = exp2f(s4[t][r]);
          s4[t][r] = p;
          rs[r] += p;
        }
    }
#pragma unroll
    for (int t = 0; t < 4; ++t)
#pragma unroll
      for (int r = 0; r < 4; ++r)
        sPw[(quad * 4 + r) * 72 + t * 16 + l15] = f2bf_fast(s4[t][r]);
#pragma unroll
    for (int kt = 0; kt < 2; ++kt) {
      bf16x8 pf = *(const bf16x8*)((char*)sPw + l15 * 144 + kt * 64 + quad * 16);
      bf16x8 v0 = *(const bf16x8*)((const char*)sV[bsel] + l15 * 144 + kt * 64 + quad * 16);
      bf16x8 v1 = *(const bf16x8*)((const char*)sV[bsel] + (16 + l15) * 144 + kt * 64 + quad * 16);
      o0 = __builtin_amdgcn_mfma_f32_16x16x32_bf16(pf, v0, o0, 0, 0, 0);
      o1 = __builtin_amdgcn_mfma_f32_16x16x32_bf16(pf, v1, o1, 0, 0, 0);
    }
  }
#pragma unroll
  for (int r = 0; r < 4; ++r) {
    float inv = 1.0f / row_sum16(rs[r]);
    int q = q0w + quad * 4 + r;
    size_t base = ((size_t)(b * SS + q)) * DD + h * 32;
    ctx[base + l15] = f2bf(o0[r] * inv);
    ctx[base + 16 + l15] = f2bf(o1[r] * inv);
  }
}

// -------- fused MLP: oproj+res+LN1 + FFN1+GELU + FFN2+res+LN2 (+head) -------
// 32 token-rows per block (grid 256). Activations live in LDS/regs; weights
// stream L2->regs (no per-K barriers). LAST: also computes the M=4 head.
template <bool LAST>
__global__ __launch_bounds__(256, 1)
void mlp_kernel(const u16* __restrict__ ctx, const u16* __restrict__ wo,
                const float* __restrict__ ob, u16* __restrict__ hb,
                const u16* __restrict__ wf1, const float* __restrict__ f1b,
                const u16* __restrict__ wf2, const float* __restrict__ f2b,
                const float* __restrict__ g1, const float* __restrict__ b1,
                const float* __restrict__ g2, const float* __restrict__ b2,
                const float* __restrict__ ow, const float* __restrict__ obias,
                float* __restrict__ out) {
  const int m0 = blockIdx.x * 32;
  const int tid = threadIdx.x;
  const int l15 = tid & 15, quad = (tid & 63) >> 4, wave = tid >> 6;
  const int ri = quad * 4;   // row base within 16-row tile for C-layout

  __shared__ float sred[512];
  __shared__ __align__(16) u16 sA2[32 * 264];    // LN1 out (stride 264: banks ok)
  __shared__ __align__(16) u16 sA3[32 * 1032];   // GELU out (stride 1032)

  const f32x4 fzero = {0.f, 0.f, 0.f, 0.f};

  // ---- stage 1: O-proj (K=256), A=ctx rows in regs ----
  bf16x8 a1[2][8];
#pragma unroll
  for (int i = 0; i < 2; ++i)
#pragma unroll
    for (int k = 0; k < 8; ++k)
      a1[i][k] = *(const bf16x8*)(ctx + (size_t)(m0 + i * 16 + l15) * DD + k * 32 + quad * 8);

  f32x4 acc[2][4];
#pragma unroll
  for (int i = 0; i < 2; ++i)
#pragma unroll
    for (int j = 0; j < 4; ++j) acc[i][j] = fzero;
#pragma unroll
  for (int k = 0; k < 8; ++k)
#pragma unroll
    for (int j = 0; j < 4; ++j) {
      bf16x8 b = *(const bf16x8*)(wo + (size_t)(wave * 64 + j * 16 + l15) * 256 + k * 32 + quad * 8);
      acc[0][j] = __builtin_amdgcn_mfma_f32_16x16x32_bf16(a1[0][k], b, acc[0][j], 0, 0, 0);
      acc[1][j] = __builtin_amdgcn_mfma_f32_16x16x32_bf16(a1[1][k], b, acc[1][j], 0, 0, 0);
    }
  // bias + residual(hb) + LN1
  float sm[2][4], sq[2][4];
#pragma unroll
  for (int i = 0; i < 2; ++i)
#pragma unroll
    for (int r = 0; r < 4; ++r) { sm[i][r] = 0.f; sq[i][r] = 0.f; }
#pragma unroll
  for (int j = 0; j < 4; ++j) {
    int col = wave * 64 + j * 16 + l15;
    float bj = ob[col];
#pragma unroll
    for (int i = 0; i < 2; ++i)
#pragma unroll
      for (int r = 0; r < 4; ++r) {
        int row = m0 + i * 16 + ri + r;
        float v = acc[i][j][r] + bj + bf2f(hb[(size_t)row * DD + col]);
        acc[i][j][r] = v; sm[i][r] += v; sq[i][r] += v * v;
      }
  }
#pragma unroll
  for (int i = 0; i < 2; ++i)
#pragma unroll
    for (int r = 0; r < 4; ++r) { sm[i][r] = row_sum16(sm[i][r]); sq[i][r] = row_sum16(sq[i][r]); }
  if (l15 == 0) {
#pragma unroll
    for (int i = 0; i < 2; ++i)
#pragma unroll
      for (int r = 0; r < 4; ++r) {
        int rr = i * 16 + ri + r;
        sred[wave * 64 + rr] = sm[i][r];
        sred[wave * 64 + 32 + rr] = sq[i][r];
      }
  }
  __syncthreads();
  float mean[2][4], rstd[2][4];
#pragma unroll
  for (int i = 0; i < 2; ++i)
#pragma unroll
    for (int r = 0; r < 4; ++r) {
      int rr = i * 16 + ri + r;
      float S = sred[rr] + sred[64 + rr] + sred[128 + rr] + sred[192 + rr];
      float S2 = sred[32 + rr] + sred[96 + rr] + sred[160 + rr] + sred[224 + rr];
      float mu = S * (1.f / 256.f);
      mean[i][r] = mu;
      rstd[i][r] = rsqrtf(S2 * (1.f / 256.f) - mu * mu + 1e-12f);
    }
#pragma unroll
  for (int j = 0; j < 4; ++j) {
    int col = wave * 64 + j * 16 + l15;
    float gj = g1[col], bj = b1[col];
#pragma unroll
    for (int i = 0; i < 2; ++i)
#pragma unroll
      for (int r = 0; r < 4; ++r) {
        float v = (acc[i][j][r] - mean[i][r]) * rstd[i][r] * gj + bj;
        sA2[(i * 16 + ri + r) * 264 + col] = f2bf(v);
      }
  }
  __syncthreads();

  // ---- stage 2: FFN1 (K=256, N=1024) + GELU ----
  bf16x8 a2[2][8];
#pragma unroll
  for (int i = 0; i < 2; ++i)
#pragma unroll
    for (int k = 0; k < 8; ++k)
      a2[i][k] = *(const bf16x8*)((const char*)sA2 + (i * 16 + l15) * 528 + k * 64 + quad * 16);
#pragma unroll
  for (int g = 0; g < 4; ++g) {
    f32x4 ac2[2][4];
#pragma unroll
    for (int i = 0; i < 2; ++i)
#pragma unroll
      for (int j = 0; j < 4; ++j) ac2[i][j] = fzero;
#pragma unroll
    for (int k = 0; k < 8; ++k)
#pragma unroll
      for (int j = 0; j < 4; ++j) {
        int n = wave * 256 + g * 64 + j * 16 + l15;
        bf16x8 b = *(const bf16x8*)(wf1 + (size_t)n * 256 + k * 32 + quad * 8);
        ac2[0][j] = __builtin_amdgcn_mfma_f32_16x16x32_bf16(a2[0][k], b, ac2[0][j], 0, 0, 0);
        ac2[1][j] = __builtin_amdgcn_mfma_f32_16x16x32_bf16(a2[1][k], b, ac2[1][j], 0, 0, 0);
      }
#pragma unroll
    for (int j = 0; j < 4; ++j) {
      int n = wave * 256 + g * 64 + j * 16 + l15;
      float bj = f1b[n];
#pragma unroll
      for (int i = 0; i < 2; ++i)
#pragma unroll
        for (int r = 0; r < 4; ++r) {
          float v = gelu_f(ac2[i][j][r] + bj);
          sA3[(i * 16 + ri + r) * 1032 + n] = f2bf(v);
        }
    }
  }
  __syncthreads();

  // ---- stage 3: FFN2 (K=1024, N=256) ----
  f32x4 ac3[2][4];
#pragma unroll
  for (int i = 0; i < 2; ++i)
#pragma unroll
    for (int j = 0; j < 4; ++j) ac3[i][j] = fzero;
#pragma unroll 8
  for (int k = 0; k < 32; ++k) {
    bf16x8 a0 = *(const bf16x8*)((const char*)sA3 + (l15) * 2064 + k * 64 + quad * 16);
    bf16x8 a1_ = *(const bf16x8*)((const char*)sA3 + (16 + l15) * 2064 + k * 64 + quad * 16);
#pragma unroll
    for (int j = 0; j < 4; ++j) {
      bf16x8 b = *(const bf16x8*)(wf2 + (size_t)(wave * 64 + j * 16 + l15) * 1024 + k * 32 + quad * 8);
      ac3[0][j] = __builtin_amdgcn_mfma_f32_16x16x32_bf16(a0, b, ac3[0][j], 0, 0, 0);
      ac3[1][j] = __builtin_amdgcn_mfma_f32_16x16x32_bf16(a1_, b, ac3[1][j], 0, 0, 0);
    }
  }
  // bias + residual(sA2 = attn_out) + LN2
#pragma unroll
  for (int i = 0; i < 2; ++i)
#pragma unroll
    for (int r = 0; r < 4; ++r) { sm[i][r] = 0.f; sq[i][r] = 0.f; }
#pragma unroll
  for (int j = 0; j < 4; ++j) {
    int col = wave * 64 + j * 16 + l15;
    float bj = f2b[col];
#pragma unroll
    for (int i = 0; i < 2; ++i)
#pragma unroll
      for (int r = 0; r < 4; ++r) {
        float v = ac3[i][j][r] + bj + bf2f(sA2[(i * 16 + ri + r) * 264 + col]);
        ac3[i][j][r] = v; sm[i][r] += v; sq[i][r] += v * v;
      }
  }
#pragma unroll
  for (int i = 0; i < 2; ++i)
#pragma unroll
    for (int r = 0; r < 4; ++r) { sm[i][r] = row_sum16(sm[i][r]); sq[i][r] = row_sum16(sq[i][r]); }
  __syncthreads();   // sred reuse guard
  if (l15 == 0) {
#pragma unroll
    for (int i = 0; i < 2; ++i)
#pragma unroll
      for (int r = 0; r < 4; ++r) {
        int rr = i * 16 + ri + r;
        sred[wave * 64 + rr] = sm[i][r];
        sred[wave * 64 + 32 + rr] = sq[i][r];
      }
  }
  __syncthreads();
#pragma unroll
  for (int i = 0; i < 2; ++i)
#pragma unroll
    for (int r = 0; r < 4; ++r) {
      int rr = i * 16 + ri + r;
      float S = sred[rr] + sred[64 + rr] + sred[128 + rr] + sred[192 + rr];
      float S2 = sred[32 + rr] + sred[96 + rr] + sred[160 + rr] + sred[224 + rr];
      float mu = S * (1.f / 256.f);
      mean[i][r] = mu;
      rstd[i][r] = rsqrtf(S2 * (1.f / 256.f) - mu * mu + 1e-12f);
    }
#pragma unroll
  for (int j = 0; j < 4; ++j) {
    int col = wave * 64 + j * 16 + l15;
    float gj = g2[col], bj = b2[col];
#pragma unroll
    for (int i = 0; i < 2; ++i)
#pragma unroll
      for (int r = 0; r < 4; ++r) {
        float v = (ac3[i][j][r] - mean[i][r]) * rstd[i][r] * gj + bj;
        ac3[i][j][r] = v;
        if constexpr (!LAST)
          hb[(size_t)(m0 + i * 16 + ri + r) * DD + col] = f2bf(v);
      }
  }
  if constexpr (LAST) {   // head: logits = h @ out_w^T + out_b  (M=4)
    float lg[2][4][4];
#pragma unroll
    for (int m = 0; m < 4; ++m) {
      float wm[4];
#pragma unroll
      for (int j = 0; j < 4; ++j) wm[j] = ow[m * 256 + wave * 64 + j * 16 + l15];
#pragma unroll
      for (int i = 0; i < 2; ++i)
#pragma unroll
        for (int r = 0; r < 4; ++r) {
          float s = 0.f;
#pragma unroll
          for (int j = 0; j < 4; ++j) s += ac3[i][j][r] * wm[j];
          lg[i][r][m] = s;
        }
    }
#pragma unroll
    for (int i = 0; i < 2; ++i)
#pragma unroll
      for (int r = 0; r < 4; ++r)
#pragma unroll
        for (int m = 0; m < 4; ++m) lg[i][r][m] = row_sum16(lg[i][r][m]);
    __syncthreads();   // sred reuse guard
    if (l15 == 0) {
#pragma unroll
      for (int i = 0; i < 2; ++i)
#pragma unroll
        for (int r = 0; r < 4; ++r)
#pragma unroll
          for (int m = 0; m < 4; ++m)
            sred[wave * 128 + (i * 16 + ri + r) * 4 + m] = lg[i][r][m];
    }
    __syncthreads();
    if (tid < 128) {
      int rr = tid >> 2, m = tid & 3;
      float s = sred[rr * 4 + m] + sred[128 + rr * 4 + m] +
                sred[256 + rr * 4 + m] + sred[384 + rr * 4 + m] + obias[m];
      out[(size_t)(m0 + rr) * 4 + m] = s;
    }
  }
}

// ---------------- launcher ---------------------------------------------------
extern "C" void kernel_launch(void* const* d_in, const int* in_sizes, int n_in,
                              void* d_out, int out_size, void* d_ws, size_t ws_size,
                              hipStream_t stream) {
  const int* x = (const int*)d_in[0];
  const float* emb_w = (const float*)d_in[1];
  const float* pe = (const float*)d_in[2];
  const float* q_w = (const float*)d_in[3];
  const float* q_b = (const float*)d_in[4];
  const float* k_w = (const float*)d_in[5];
  const float* k_b = (const float*)d_in[6];
  const float* v_w = (const float*)d_in[7];
  const float* v_b = (const float*)d_in[8];
  const float* o_w = (const float*)d_in[9];
  const float* o_b = (const float*)d_in[10];
  const float* ln1_g = (const float*)d_in[11];
  const float* ln1_b = (const float*)d_in[12];
  const float* f1_w = (const float*)d_in[13];
  const float* f1_b = (const float*)d_in[14];
  const float* f2_w = (const float*)d_in[15];
  const float* f2_b = (const float*)d_in[16];
  const float* ln2_g = (const float*)d_in[17];
  const float* ln2_b = (const float*)d_in[18];
  const float* out_w = (const float*)d_in[19];
  const float* out_b = (const float*)d_in[20];
  float* out = (float*)d_out;

  char* w = (char*)d_ws;
  const size_t MB = 1ull << 20;
  u16* hb    = (u16*)(w + 0 * MB);    // [8192,256] bf16
  u16* qb    = (u16*)(w + 4 * MB);
  u16* kbuf  = (u16*)(w + 8 * MB);
  u16* vtb   = (u16*)(w + 12 * MB);   // V transposed [64 bh][32 d][1024 s]
  u16* ctxb  = (u16*)(w + 16 * MB);
  u16* wqkv  = (u16*)(w + 48 * MB);   // [L][768][256] bf16 (q/k/v stacked per layer)
  u16* wo    = (u16*)(w + 52 * MB);   // [L][256][256] bf16
  u16* wf1   = (u16*)(w + 54 * MB);   // [L][1024][256] bf16
  u16* wf2   = (u16*)(w + 56 * MB);   // [L][256][1024] bf16
  float* bqkv = (float*)(w + 58 * MB); // [L][768] f32

  CvtArgs ca;
  // q/k/v weights -> interleaved [L][768][256]
  ca.src[0] = q_w;  ca.dst[0] = wqkv;           ca.n4[0] = 65536;  ca.bf[0] = 1; ca.sh[0] = 14; ca.ls[0] = 49152;
  ca.src[1] = k_w;  ca.dst[1] = wqkv + 65536;   ca.n4[1] = 65536;  ca.bf[1] = 1; ca.sh[1] = 14; ca.ls[1] = 49152;
  ca.src[2] = v_w;  ca.dst[2] = wqkv + 131072;  ca.n4[2] = 65536;  ca.bf[2] = 1; ca.sh[2] = 14; ca.ls[2] = 49152;
  ca.src[3] = o_w;  ca.dst[3] = wo;             ca.n4[3] = 65536;  ca.bf[3] = 1; ca.sh[3] = 18; ca.ls[3] = 0;
  ca.src[4] = f1_w; ca.dst[4] = wf1;            ca.n4[4] = 262144; ca.bf[4] = 1; ca.sh[4] = 18; ca.ls[4] = 0;
  ca.src[5] = f2_w; ca.dst[5] = wf2;            ca.n4[5] = 262144; ca.bf[5] = 1; ca.sh[5] = 18; ca.ls[5] = 0;
  // q/k/v biases -> interleaved [L][768] f32
  ca.src[6] = q_b;  ca.dst[6] = bqkv;           ca.n4[6] = 256;    ca.bf[6] = 0; ca.sh[6] = 6;  ca.ls[6] = 192;
  ca.src[7] = k_b;  ca.dst[7] = bqkv + 256;     ca.n4[7] = 256;    ca.bf[7] = 0; ca.sh[7] = 6;  ca.ls[7] = 192;
  ca.src[8] = v_b;  ca.dst[8] = bqkv + 512;     ca.n4[8] = 256;    ca.bf[8] = 0; ca.sh[8] = 6;  ca.ls[8] = 192;
  cvt_kernel<<<dim3(1024, 9), 256, 0, stream>>>(ca);

  embed_kernel<<<2048, 256, 0, stream>>>(x, emb_w, pe, hb);

  for (int l = 0; l < 4; ++l) {
    qkv_kernel<<<256, 256, 0, stream>>>(hb, wqkv + (size_t)l * 196608,
                                        bqkv + l * 768, qb, kbuf, vtb);
    attn_kernel<<<dim3(16, 64), 256, 0, stream>>>(qb, kbuf, vtb, ctxb);
    const u16* wol = wo + (size_t)l * 65536;
    const u16* wf1l = wf1 + (size_t)l * 262144;
    const u16* wf2l = wf2 + (size_t)l * 262144;
    if (l < 3) {
      mlp_kernel<false><<<256, 256, 0, stream>>>(
          ctxb, wol, o_b + l * 256, hb, wf1l, f1_b + l * 1024, wf2l,
          f2_b + l * 256, ln1_g + l * 256, ln1_b + l * 256,
          ln2_g + l * 256, ln2_b + l * 256, nullptr, nullptr, nullptr);
    } else {
      mlp_kernel<true><<<256, 256, 0, stream>>>(
          ctxb, wol, o_b + l * 256, hb, wf1l, f1_b + l * 1024, wf2l,
          f2_b + l * 256, ln1_g + l * 256, ln1_b + l * 256,
          ln2_g + l * 256, ln2_b + l * 256, out_w, out_b, out);
    }
  }
}